// Round 9
// baseline (1874.929 us; speedup 1.0000x reference)
//
#include <hip/hip_runtime.h>

// LSTM, B=512 x T=1024, H=100, input_size=1.  MFMA persistent-RNN, v4:
// single-barrier fused-cell structure.
//
// R8 post-mortem: 2-barrier skeleton costs ~2000 cyc/step beyond the 1090
// cyc MFMA floor (two LDS round-trips + two barrier drains). Fixes here:
// 1) Row permutation m' = 4*unit + gate: D-lane (quad,reg) of tile mt holds
//    ALL 4 gates of unit j=4mt+quad -> LSTM cell computed in-register by the
//    MFMA wave. No gate LDS matrix, no separate cell phase.
// 2) K-padding slots: B[100]=x_t, B[101]=1.0; A[.][100]=W_ih, A[.][101]=bias
//    -> input projection + biases ride the MFMA.
// 3) Tile 25 row 400 = W_out (b_out at k=101) -> output projection is one
//    extra MFMA tile, naturally one step lagged. Phase C gone.
// 4) Ping-pong BH buffers: read parity p, write parity 1-p -> ONE
//    __syncthreads per step.
// Precision: W 2-term exact fp16 split (lo prescaled 4096); h,x single fp16.
// Verified layouts (m89): A[m=lane&15][k=quad*8+j]; B[k=quad*8+j][n=lane&15];
// D[row=4*quad+reg][col=lane&15].

#define HID   100
#define TLEN  1024
#define BLOCK 512   // 8 waves

typedef __attribute__((ext_vector_type(8))) _Float16 half8;
typedef __attribute__((ext_vector_type(4))) float f32x4;

#define MFMA16(A, B, C) __builtin_amdgcn_mfma_f32_16x16x32_f16(A, B, C, 0, 0, 0)

__global__ __launch_bounds__(BLOCK) void lstm_fused(
    const float* __restrict__ input,   // [B, T]
    const float* __restrict__ W_ih,    // [4H]
    const float* __restrict__ W_hh,    // [4H, H]
    const float* __restrict__ b_ih,    // [4H]
    const float* __restrict__ b_hh,    // [4H]
    const float* __restrict__ W_out,   // [H]
    const float* __restrict__ b_out,   // [1]
    float* __restrict__ out)           // [B, T]
{
    const int tid  = threadIdx.x;
    const int b0   = blockIdx.x * 2;
    const int wv   = tid >> 6;
    const int lane = tid & 63;
    const int col  = lane & 15;        // A m-row / D n-col (batch slot)
    const int quad = lane >> 4;        // A k-chunk / D row-block
    const int nb   = col & 1;          // batch the B-read follows (dups ok)

    __shared__ __align__(16) float    in_s[2][TLEN + 4];  // +pad for x[T]=0
    __shared__ __align__(16) _Float16 BH[2][2][128];      // [parity][batch][k]

    // Stage inputs (coalesced); pad; zero both BH buffers (h0=0, k-pad=0).
    for (int i = tid; i < TLEN; i += BLOCK) {
        in_s[0][i] = input[(b0 + 0) * TLEN + i];
        in_s[1][i] = input[(b0 + 1) * TLEN + i];
    }
    if (tid < 2) in_s[tid][TLEN] = 0.f;
    ((_Float16*)BH)[tid] = (_Float16)0.f;     // 512 halfs = BLOCK threads
    __syncthreads();
    if (tid < 2) {                            // constants + x_0
        BH[0][tid][101] = (_Float16)1.f;
        BH[1][tid][101] = (_Float16)1.f;
        BH[0][tid][100] = (_Float16)input[(b0 + tid) * TLEN];
    }

    // ---- Tile assignment: 25 gate tiles + tile 25 = W_out row.
    int tiles[4];
    if (wv < 6)       { tiles[0] = 3*wv; tiles[1] = 3*wv+1; tiles[2] = 3*wv+2; tiles[3] = 25; }
    else if (wv == 6) { tiles[0] = 18;   tiles[1] = 19;     tiles[2] = 20;     tiles[3] = 25; }
    else              { tiles[0] = 21;   tiles[1] = 22;     tiles[2] = 23;     tiles[3] = 24; }
    const bool has4 = (wv >= 6);   // slot 3 active (wv6: out tile; wv7: gates)

    // ---- Persistent A-fragments: exact fp16 hi/lo split, permuted rows.
    // Tile mt<25, A-row col -> gate g=col&3, unit u=4mt+(col>>2),
    // W_hh row r=g*100+u; k=100 -> W_ih[r]; k=101 -> bias[r].
    // Tile 25: col==0 -> W_out (k<100), b_out at k=101; other cols zero.
    half8 wHi[4][4], wLo[4][4];
    #pragma unroll
    for (int m = 0; m < 4; ++m) {
        const int mt = tiles[m];
        const int g  = col & 3;
        const int u  = 4 * mt + (col >> 2);
        const int r  = g * HID + u;
        #pragma unroll
        for (int kt = 0; kt < 4; ++kt) {
            half8 hi, lo;
            #pragma unroll
            for (int j = 0; j < 8; ++j) {
                const int k = 32 * kt + 8 * quad + j;
                float w = 0.f;
                if (mt < 25) {
                    if (k < HID)        w = W_hh[r * HID + k];
                    else if (k == HID)  w = W_ih[r];
                    else if (k == 101)  w = b_ih[r] + b_hh[r];
                } else if (col == 0) {
                    if (k < HID)        w = W_out[k];
                    else if (k == 101)  w = b_out[0];
                }
                _Float16 wh = (_Float16)w;
                hi[j] = wh;
                lo[j] = (_Float16)((w - (float)wh) * 4096.f);  // exact residual
            }
            {   // opacity barrier: no remat/sink into the t-loop (R2 lesson)
                int* a = (int*)&hi; int* b = (int*)&lo;
                asm volatile("" : "+v"(a[0]), "+v"(a[1]), "+v"(a[2]), "+v"(a[3]));
                asm volatile("" : "+v"(b[0]), "+v"(b[1]), "+v"(b[2]), "+v"(b[3]));
            }
            wHi[m][kt] = hi; wLo[m][kt] = lo;
        }
    }

    float cst[4] = {0.f, 0.f, 0.f, 0.f};   // cell state per tile slot
    const float slo = 2.44140625e-4f;      // 2^-12 (undo the 4096 prescale)
    __syncthreads();

    for (int t = 0; ; ++t) {
        const int p = t & 1;
        const int q = 1 - p;

        // B-fragments: 4 ds_read_b128, 8 addrs/wave, 2 addrs/bank (free).
        half8 bh[4];
        #pragma unroll
        for (int kt = 0; kt < 4; ++kt)
            bh[kt] = *(const half8*)&BH[p][nb][32 * kt + 8 * quad];

        f32x4 aH0 = {0,0,0,0}, aH1 = {0,0,0,0}, aH2 = {0,0,0,0}, aH3 = {0,0,0,0};
        f32x4 aL0 = {0,0,0,0}, aL1 = {0,0,0,0}, aL2 = {0,0,0,0}, aL3 = {0,0,0,0};
        #pragma unroll
        for (int kt = 0; kt < 4; ++kt) {
            aH0 = MFMA16(wHi[0][kt], bh[kt], aH0);
            aL0 = MFMA16(wLo[0][kt], bh[kt], aL0);
            aH1 = MFMA16(wHi[1][kt], bh[kt], aH1);
            aL1 = MFMA16(wLo[1][kt], bh[kt], aL1);
            aH2 = MFMA16(wHi[2][kt], bh[kt], aH2);
            aL2 = MFMA16(wLo[2][kt], bh[kt], aL2);
            if (has4) {
                aH3 = MFMA16(wHi[3][kt], bh[kt], aH3);
                aL3 = MFMA16(wLo[3][kt], bh[kt], aL3);
            }
        }

        const f32x4 g0 = aH0 + aL0 * slo;
        const f32x4 g1 = aH1 + aL1 * slo;
        const f32x4 g2 = aH2 + aL2 * slo;
        const f32x4 g3 = aH3 + aL3 * slo;   // wv6: out row; wv7: gates; else dead

        // Output store (wv6, tile 25, D row 0 = m'=400): lagged one step.
        // Issued before the cell so the vmcnt drain overlaps cell compute.
        if (wv == 6 && t > 0 && quad == 0 && col < 2)
            out[(b0 + col) * TLEN + (t - 1)] = g3[0];

        if (t == TLEN) break;   // last iteration only produces out[T-1]

        // ---- In-register LSTM cell: slot gates g[0..3] = i,f,g,o of unit
        // j = 4*tiles[m]+quad, batch=col. Only col<2 lanes write h.
        auto cell = [&](const f32x4 gg, float& c, const int mt) {
            float is = 1.f / (1.f + __expf(-gg[0]));
            float fs = 1.f / (1.f + __expf(-gg[1]));
            float gt = 1.f - 2.f / (__expf(2.f * gg[2]) + 1.f);
            float os = 1.f / (1.f + __expf(-gg[3]));
            c = fmaf(fs, c, is * gt);
            float hv = os * (1.f - 2.f / (__expf(2.f * c) + 1.f));
            if (col < 2) BH[q][col][4 * mt + quad] = (_Float16)hv;
        };
        cell(g0, cst[0], tiles[0]);
        cell(g1, cst[1], tiles[1]);
        cell(g2, cst[2], tiles[2]);
        if (wv == 7) cell(g3, cst[3], tiles[3]);

        // x_{t+1} into the write buffer (in_s[.][TLEN] pad = 0 covers t+1==T).
        if (wv == 0 && quad == 0 && col < 2)
            BH[q][col][100] = (_Float16)in_s[col][t + 1];

        __syncthreads();   // the ONLY barrier per step
    }
}

extern "C" void kernel_launch(void* const* d_in, const int* in_sizes, int n_in,
                              void* d_out, int out_size, void* d_ws, size_t ws_size,
                              hipStream_t stream) {
    const float* input = (const float*)d_in[0];
    const float* W_ih  = (const float*)d_in[1];
    const float* W_hh  = (const float*)d_in[2];
    const float* b_ih  = (const float*)d_in[3];
    const float* b_hh  = (const float*)d_in[4];
    const float* W_out = (const float*)d_in[5];
    const float* b_out = (const float*)d_in[6];
    float* out = (float*)d_out;

    const int B = in_sizes[0] / TLEN;  // 512
    lstm_fused<<<B / 2, BLOCK, 0, stream>>>(input, W_ih, W_hh, b_ih, b_hh,
                                            W_out, b_out, out);
}

// Round 10
// 1745.614 us; speedup vs baseline: 1.0741x; 1.0741x over previous
//
#include <hip/hip_runtime.h>

// LSTM, B=512 x T=1024, H=100, input_size=1.  MFMA persistent-RNN, v5:
// 16 batches per block (N-dim FULL), single barrier, in-register cell.
//
// R9 post-mortem: fused cell replicated on 16 cols with only 2 real batches
// -> 8x wasted transcendental VALU (58% VALUBusy), exec-mask saves nothing
// on wave64. Step time is per-block critical path and the chip is 8x
// over-provisioned -> 32 blocks x 16 batches: same per-step work as R9 but
// every lane's cell is real.
// - Row permutation m' = 4*unit+gate: D regs 0..3 of lane (quad,col) = gates
//   i,f,g,o of unit 4mt+quad, batch col -> cell fully in-register.
// - Acc seeded with persistent fp32 bias fragment (exact biases, no zero-init
//   for the HI term, no bias K-column).
// - B K-slot 100 carries x_t (A k=100 = W_ih hi/lo); tile 25 row 0 = W_out
//   (acc seeded b_out) -> output projection rides the MFMA, lagged 1 step.
// - x streamed from global by wave 1 lanes 0..15, prefetched 2 steps ahead.
// - BH[parity][col][128] halfs with per-col chunk rotation (chunk+col)&15:
//   b128 B-reads hit the 8-round minimum, h/x writes spread banks.
// - ONE __syncthreads per step (ping-pong parity).
// Precision: W exact fp16 hi/lo (lo prescaled 4096); h,x single fp16.
// Verified layouts (m89): A[m=lane&15][k=quad*8+j]; B[k=quad*8+j][n=lane&15];
// D[row=4*quad+reg][col=lane&15].

#define HID   100
#define TLEN  1024
#define NB    16     // batches per block
#define BLOCK 512    // 8 waves

typedef __attribute__((ext_vector_type(8))) _Float16 half8;
typedef __attribute__((ext_vector_type(4))) float f32x4;

#define MFMA16(A, B, C) __builtin_amdgcn_mfma_f32_16x16x32_f16(A, B, C, 0, 0, 0)

__global__ __launch_bounds__(BLOCK) void lstm_wide(
    const float* __restrict__ input,   // [B, T]
    const float* __restrict__ W_ih,    // [4H]
    const float* __restrict__ W_hh,    // [4H, H]
    const float* __restrict__ b_ih,    // [4H]
    const float* __restrict__ b_hh,    // [4H]
    const float* __restrict__ W_out,   // [H]
    const float* __restrict__ b_out,   // [1]
    float* __restrict__ out)           // [B, T]
{
    const int tid  = threadIdx.x;
    const int b0   = blockIdx.x * NB;
    const int wv   = tid >> 6;
    const int lane = tid & 63;
    const int c    = lane & 15;        // A row-in-tile / D batch col
    const int quad = lane >> 4;        // A k-chunk / D row-block

    // [parity][batch col][128 halfs as 16 chunks of 8, rotated by col]
    __shared__ __align__(16) _Float16 BH[2][NB][128];

    // Zero both parities (h0 = 0, K-pad = 0). 2*16*128 halfs = 2048 ints.
    {
        int* bz = (int*)BH;
        for (int i = tid; i < 2048; i += BLOCK) bz[i] = 0;
    }

    // ---- Tile assignment: 25 gate tiles + tile 25 = W_out row.
    // {4,3,3,3,3,3,3,4}: any wave->SIMD pairing yields <=7-8 tiles/SIMD.
    int tiles[4];
    if (wv == 0)      { tiles[0]=0;      tiles[1]=1;      tiles[2]=2;      tiles[3]=3;  }
    else if (wv == 7) { tiles[0]=22;     tiles[1]=23;     tiles[2]=24;     tiles[3]=25; }
    else              { tiles[0]=3*wv+1; tiles[1]=3*wv+2; tiles[2]=3*wv+3; tiles[3]=3*wv+3; }
    const bool has4  = (wv == 0) || (wv == 7);   // slot 3 does MFMA
    const bool isout = (wv == 7);                // slot 3 is the out tile

    // ---- Persistent A-fragments: exact fp16 hi/lo split, permuted rows.
    half8 wHi[4][4], wLo[4][4];
    #pragma unroll
    for (int m = 0; m < 4; ++m) {
        const int mt = tiles[m];
        #pragma unroll
        for (int kt = 0; kt < 4; ++kt) {
            half8 hi, lo;
            #pragma unroll
            for (int j = 0; j < 8; ++j) {
                const int k = 32 * kt + 8 * quad + j;
                float w = 0.f;
                if (mt < 25) {
                    const int r = (c & 3) * HID + (4 * mt + (c >> 2));
                    if (k < HID)       w = W_hh[r * HID + k];
                    else if (k == HID) w = W_ih[r];
                } else if (c == 0 && k < HID) {
                    w = W_out[k];
                }
                _Float16 wh = (_Float16)w;
                hi[j] = wh;
                lo[j] = (_Float16)((w - (float)wh) * 4096.f);
            }
            {   // opacity: no remat/sink into the t-loop (R2 lesson)
                int* a = (int*)&hi; int* b = (int*)&lo;
                asm volatile("" : "+v"(a[0]), "+v"(a[1]), "+v"(a[2]), "+v"(a[3]));
                asm volatile("" : "+v"(b[0]), "+v"(b[1]), "+v"(b[2]), "+v"(b[3]));
            }
            wHi[m][kt] = hi; wLo[m][kt] = lo;
        }
    }

    // ---- Persistent fp32 bias fragments (acc C-seed; exact, col-invariant).
    f32x4 biasf[4];
    #pragma unroll
    for (int m = 0; m < 4; ++m) {
        const int mt = tiles[m];
        #pragma unroll
        for (int r = 0; r < 4; ++r) {       // D row = 4*quad + r -> gate r, unit u
            float bv = 0.f;
            if (mt < 25) {
                const int row = r * HID + (4 * mt + quad);
                bv = b_ih[row] + b_hh[row];
            } else if (quad == 0 && r == 0) {
                bv = b_out[0];
            }
            asm volatile("" : "+v"(bv));    // keep resident
            biasf[m][r] = bv;
        }
    }

    __syncthreads();   // zeros visible

    // ---- x streaming (wave 1, lanes 0..15 = batch col): 2-step prefetch.
    float xc = 0.f, xn = 0.f;
    if (wv == 1 && lane < 16) {
        const float* xp = input + (b0 + lane) * TLEN;
        BH[0][lane][((12 + lane) & 15) * 8 + 4] = (_Float16)xp[0];  // x_0, chunk 12 pos 4
        xc = xp[1];
        xn = xp[2];
    }
    __syncthreads();

    float cst[4] = {0.f, 0.f, 0.f, 0.f};   // cell state per slot (unit 4mt+quad, batch c)
    const float slo = 2.44140625e-4f;      // 2^-12: undo the 4096 prescale

    for (int t = 0; ; ++t) {
        const int p = t & 1;
        const int q = p ^ 1;

        // B-fragments: 4 ds_read_b128; rotation -> minimum 8-round service.
        half8 bh[4];
        #pragma unroll
        for (int kt = 0; kt < 4; ++kt) {
            const int ch = (4 * kt + quad + c) & 15;
            bh[kt] = *(const half8*)&BH[p][c][ch * 8];
        }

        f32x4 aH[4], aL[4];
        #pragma unroll
        for (int m = 0; m < 4; ++m) { aH[m] = biasf[m]; aL[m] = (f32x4){0,0,0,0}; }
        #pragma unroll
        for (int kt = 0; kt < 4; ++kt) {
            aH[0] = MFMA16(wHi[0][kt], bh[kt], aH[0]);
            aL[0] = MFMA16(wLo[0][kt], bh[kt], aL[0]);
            aH[1] = MFMA16(wHi[1][kt], bh[kt], aH[1]);
            aL[1] = MFMA16(wLo[1][kt], bh[kt], aL[1]);
            aH[2] = MFMA16(wHi[2][kt], bh[kt], aH[2]);
            aL[2] = MFMA16(wLo[2][kt], bh[kt], aL[2]);
            if (has4) {
                aH[3] = MFMA16(wHi[3][kt], bh[kt], aH[3]);
                aL[3] = MFMA16(wLo[3][kt], bh[kt], aL[3]);
            }
        }

        // Output projection (wv7 slot 3, D row 0 = lanes 0..15): out[t-1].
        if (isout && t > 0 && lane < 16) {
            f32x4 ov = aH[3] + aL[3] * slo;
            out[(b0 + lane) * TLEN + (t - 1)] = ov[0];
        }

        if (t == TLEN) break;   // final iteration only emits out[T-1]

        // In-register LSTM cell — every lane is a real (unit, batch) cell.
        #pragma unroll
        for (int m = 0; m < 3; ++m) {
            f32x4 gg = aH[m] + aL[m] * slo;
            float is = 1.f / (1.f + __expf(-gg[0]));
            float fs = 1.f / (1.f + __expf(-gg[1]));
            float gt = 1.f - 2.f / (__expf(2.f * gg[2]) + 1.f);
            float os = 1.f / (1.f + __expf(-gg[3]));
            cst[m] = fmaf(fs, cst[m], is * gt);
            float hv = os * (1.f - 2.f / (__expf(2.f * cst[m]) + 1.f));
            const int u = 4 * tiles[m] + quad;
            BH[q][c][(((u >> 3) + c) & 15) * 8 + (u & 7)] = (_Float16)hv;
        }
        if (wv == 0) {          // wv0's 4th gate slot
            f32x4 gg = aH[3] + aL[3] * slo;
            float is = 1.f / (1.f + __expf(-gg[0]));
            float fs = 1.f / (1.f + __expf(-gg[1]));
            float gt = 1.f - 2.f / (__expf(2.f * gg[2]) + 1.f);
            float os = 1.f / (1.f + __expf(-gg[3]));
            cst[3] = fmaf(fs, cst[3], is * gt);
            float hv = os * (1.f - 2.f / (__expf(2.f * cst[3]) + 1.f));
            const int u = 4 * tiles[3] + quad;
            BH[q][c][(((u >> 3) + c) & 15) * 8 + (u & 7)] = (_Float16)hv;
        }

        // x_{t+1} into the write parity; refill the 2-deep prefetch pipe.
        if (wv == 1 && lane < 16) {
            BH[q][lane][((12 + lane) & 15) * 8 + 4] = (_Float16)xc;
            xc = xn;
            const int idx = (t + 3 < TLEN) ? (t + 3) : (TLEN - 1);
            xn = input[(b0 + lane) * TLEN + idx];
        }

        __syncthreads();        // the ONLY barrier per step
    }
}

extern "C" void kernel_launch(void* const* d_in, const int* in_sizes, int n_in,
                              void* d_out, int out_size, void* d_ws, size_t ws_size,
                              hipStream_t stream) {
    const float* input = (const float*)d_in[0];
    const float* W_ih  = (const float*)d_in[1];
    const float* W_hh  = (const float*)d_in[2];
    const float* b_ih  = (const float*)d_in[3];
    const float* b_hh  = (const float*)d_in[4];
    const float* W_out = (const float*)d_in[5];
    const float* b_out = (const float*)d_in[6];
    float* out = (float*)d_out;

    const int B = in_sizes[0] / TLEN;  // 512
    lstm_wide<<<B / NB, BLOCK, 0, stream>>>(input, W_ih, W_hh, b_ih, b_hh,
                                            W_out, b_out, out);
}